// Round 12
// baseline (1324.820 us; speedup 1.0000x reference)
//
#include <hip/hip_runtime.h>
#include <hip/hip_bf16.h>

// Problem constants (from reference)
#define NN 100000      // nodes
#define FF 128         // F_IN
#define HH 64          // HID
#define BN_EPS 1e-5f

typedef unsigned int uint_t;

// ---------------- bf16 helpers (RNE) ----------------
__device__ __forceinline__ float bflo(uint_t u) { return __uint_as_float(u << 16); }
__device__ __forceinline__ float bfhi(uint_t u) { return __uint_as_float(u & 0xFFFF0000u); }
__device__ __forceinline__ unsigned short f2bf(float f) {
    uint_t a = __float_as_uint(f); a += 0x7FFF + ((a >> 16) & 1); return (unsigned short)(a >> 16);
}
__device__ __forceinline__ uint_t f2bf2(float lo, float hi) {
    uint_t a = __float_as_uint(lo); a += 0x7FFF + ((a >> 16) & 1);
    uint_t b = __float_as_uint(hi); b += 0x7FFF + ((b >> 16) & 1);
    return (a >> 16) | (b & 0xFFFF0000u);
}

// ---------------- dtype detection (int64 vs int32 edge/batch) ----------------
__global__ void k_detect(const unsigned* __restrict__ ei, int* __restrict__ flag) {
    if (threadIdx.x == 0 && blockIdx.x == 0) {
        unsigned o = 0;
        for (int i = 1; i < 32; i += 2) o |= ei[i];   // high words if int64
        *flag = (o == 0) ? 1 : 0;                      // 1 => int64
    }
}

__device__ __forceinline__ int load_idx(const void* p, int i, int is64) {
    return is64 ? (int)((const long long*)p)[i] : ((const int*)p)[i];
}

// ---------------- degree count ----------------
__global__ void k_count(const void* __restrict__ ei, int E, const int* __restrict__ flag,
                        int* __restrict__ counts) {
    int e = blockIdx.x * blockDim.x + threadIdx.x;
    if (e >= E) return;
    int is64 = *flag;
    int d = load_idx(ei, E + e, is64);   // dst row is second half
    atomicAdd(&counts[d], 1);
}

// ---------------- dinv + per-graph node counts ----------------
__global__ void k_dinv(const int* __restrict__ counts, float* __restrict__ dinv,
                       const void* __restrict__ bat, const int* __restrict__ flag,
                       int* __restrict__ gcnt, int N) {
    int i = blockIdx.x * blockDim.x + threadIdx.x;
    if (i >= N) return;
    float deg = (float)counts[i] + 1.0f;
    dinv[i] = rsqrtf(deg);
    int is64 = *flag;
    int b = load_idx(bat, i, is64);
    atomicAdd(&gcnt[b], 1);
}

// ---------------- 3-kernel exclusive scan (chunk = 512) ----------------
__global__ void k_scan1(const int* __restrict__ counts, int* __restrict__ partial, int N) {
    __shared__ int s[512];
    int t = threadIdx.x;
    int i = blockIdx.x * 512 + t;
    int v = (i < N) ? counts[i] : 0;
    s[t] = v; __syncthreads();
    for (int off = 256; off; off >>= 1) {
        if (t < off) s[t] += s[t + off];
        __syncthreads();
    }
    if (t == 0) partial[blockIdx.x] = s[0];
}

__global__ void k_scan2(int* __restrict__ partial, int nch) {
    __shared__ int s[256];
    int t = threadIdx.x;
    int v = (t < nch) ? partial[t] : 0;
    s[t] = v; __syncthreads();
    for (int off = 1; off < 256; off <<= 1) {
        int add = (t >= off) ? s[t - off] : 0;
        __syncthreads();
        s[t] += add;
        __syncthreads();
    }
    if (t < nch) partial[t] = s[t] - v;   // exclusive
}

__global__ void k_scan3(const int* __restrict__ counts, const int* __restrict__ partial,
                        int* __restrict__ rp, int N, int E) {
    __shared__ int s[512];
    int t = threadIdx.x;
    int i = blockIdx.x * 512 + t;
    int v = (i < N) ? counts[i] : 0;
    s[t] = v; __syncthreads();
    for (int off = 1; off < 512; off <<= 1) {
        int add = (t >= off) ? s[t - off] : 0;
        __syncthreads();
        s[t] += add;
        __syncthreads();
    }
    if (i < N) rp[i] = partial[blockIdx.x] + s[t] - v;
    if (i == N) rp[N] = E;
}

// ---------------- CSR fill: packed {src, w} ----------------
__global__ void k_fill(const void* __restrict__ ei, int E, const int* __restrict__ flag,
                       const float* __restrict__ dinv, const int* __restrict__ rp,
                       int* __restrict__ fillcnt, int2* __restrict__ cw) {
    int e = blockIdx.x * blockDim.x + threadIdx.x;
    if (e >= E) return;
    int is64 = *flag;
    int s = load_idx(ei, e, is64);
    int d = load_idx(ei, E + e, is64);
    float w = dinv[s] * dinv[d];
    int pos = rp[d] + atomicAdd(&fillcnt[d], 1);
    int2 p; p.x = s; p.y = __float_as_int(w);
    cw[pos] = p;
}

// ---------------- BN constant folding ----------------
__global__ void k_prep(const float* b1, const float* g1, const float* be1,
                       const float* m1, const float* v1,
                       const float* b2, const float* g2, const float* be2,
                       const float* m2, const float* v2,
                       float* sc1, float* sh1, float* sc2, float* sh2) {
    int f = threadIdx.x;
    if (f < HH) {
        float s1 = g1[f] * rsqrtf(v1[f] + BN_EPS);
        sc1[f] = s1; sh1[f] = (b1[f] - m1[f]) * s1 + be1[f];
        float s2 = g2[f] * rsqrtf(v2[f] + BN_EPS);
        sc2[f] = s2; sh2[f] = (b2[f] - m2[f]) * s2 + be2[f];
    }
}

// ---------------- dense GEMM: out[n][f] = bf16(sum_k x[n][k] * W[f][k]) ----------
__device__ __forceinline__ float ldf(const float* p, int i) { return p[i]; }
__device__ __forceinline__ float ldf(const unsigned short* p, int i) {
    return __uint_as_float((uint_t)p[i] << 16);
}

template <int K, int NPB, typename Tin>
__global__ void k_gemm(const Tin* __restrict__ x, const float* __restrict__ W,
                       unsigned short* __restrict__ out, int N) {
    __shared__ float wT[K * (HH + 1)];
    __shared__ float xs[NPB * K];
    const int TB = NPB * 64;
    int t = threadIdx.x;
    for (int idx = t; idx < K * HH; idx += TB) {
        int f = idx / K, k = idx % K;
        wT[k * (HH + 1) + f] = W[idx];
    }
    int nb = blockIdx.x * NPB;
    for (int idx = t; idx < NPB * K; idx += TB) {
        int gi = nb * K + idx;
        xs[idx] = (gi < N * K) ? ldf(x, gi) : 0.0f;
    }
    __syncthreads();
    int f = t & 63, nl = t >> 6;
    float acc = 0.0f;
#pragma unroll
    for (int k = 0; k < K; k++)
        acc += xs[nl * K + k] * wT[k * (HH + 1) + f];
    int n = nb + nl;
    if (n < N) out[n * HH + f] = f2bf(acc);
}

// ---------------- aggregation: unrolled 64-slot batch, bf16 rows --------------
// Wave per node. ONE coalesced 512B instruction loads 64 cw entries (one/lane);
// weights masked BEFORE shfl (exec-safe). Lane layout: q = lane>>3 (8 edge
// slots), fl = lane&7 (uint4 = 8 bf16 of the 128B row). The batch body is a
// FIXED #pragma unroll of 8 gather instructions issued back-to-back -> ~8 loads
// in flight per wave (R11 had ~2: dynamic trip count forced waitcnt each iter).
// Dummy slots (beyond navail) carry w=0 and duplicate the last row (L1 hit).
template <int LAYER>
__global__ void k_agg(const unsigned short* __restrict__ h, const int2* __restrict__ cw,
                      const int* __restrict__ rp, const float* __restrict__ dinv,
                      const float* __restrict__ sc, const float* __restrict__ sh,
                      unsigned short* __restrict__ out,
                      const void* __restrict__ bat, const int* __restrict__ flag,
                      const float* __restrict__ Wl, float* __restrict__ gsum, int N) {
    int wid = (int)((blockIdx.x * blockDim.x + threadIdx.x) >> 6);
    if (wid >= N) return;
    int lane = threadIdx.x & 63;
    int q  = lane >> 3;      // edge slot within 8-edge group
    int fl = lane & 7;       // uint4 chunk (8 bf16) of the row
    const uint4* __restrict__ h4 = (const uint4*)h;   // row stride = 8 uint4

    int s = rp[wid], e = rp[wid + 1];
    float a0=0.f,a1=0.f,a2=0.f,a3=0.f,a4=0.f,a5=0.f,a6=0.f,a7=0.f;

    for (int base = s; base < e; base += 64) {
        int navail = e - base; if (navail > 64) navail = 64;
        int li = base + (lane < navail ? lane : navail - 1);
        int2 pk = cw[li];
        int   sl = pk.x;
        float wl = (lane < navail) ? __int_as_float(pk.y) : 0.f;  // mask BEFORE shfl

        int srow[8]; float wgt[8];
#pragma unroll
        for (int g = 0; g < 8; g++) {
            srow[g] = __shfl(sl, g * 8 + q);
            wgt[g]  = __shfl(wl, g * 8 + q);
        }
        uint4 r[8];
#pragma unroll
        for (int g = 0; g < 8; g++) r[g] = h4[(size_t)srow[g] * 8 + fl];
#pragma unroll
        for (int g = 0; g < 8; g++) {
            float w = wgt[g];
            a0 += w * bflo(r[g].x); a1 += w * bfhi(r[g].x);
            a2 += w * bflo(r[g].y); a3 += w * bfhi(r[g].y);
            a4 += w * bflo(r[g].z); a5 += w * bfhi(r[g].z);
            a6 += w * bflo(r[g].w); a7 += w * bfhi(r[g].w);
        }
    }
    // combine the 8 edge slots (lane bits 3,4,5)
#pragma unroll
    for (int off = 8; off <= 32; off <<= 1) {
        a0 += __shfl_xor(a0, off); a1 += __shfl_xor(a1, off);
        a2 += __shfl_xor(a2, off); a3 += __shfl_xor(a3, off);
        a4 += __shfl_xor(a4, off); a5 += __shfl_xor(a5, off);
        a6 += __shfl_xor(a6, off); a7 += __shfl_xor(a7, off);
    }

    // self-loop term (every lane computes; only lanes 0-7 consume)
    float di = dinv[wid];
    float di2 = di * di;
    uint4 sr = h4[(size_t)wid * 8 + fl];
    a0 += di2 * bflo(sr.x); a1 += di2 * bfhi(sr.x);
    a2 += di2 * bflo(sr.y); a3 += di2 * bfhi(sr.y);
    a4 += di2 * bflo(sr.z); a5 += di2 * bfhi(sr.z);
    a6 += di2 * bflo(sr.w); a7 += di2 * bfhi(sr.w);

    // BN + ReLU on this lane's 8 features
    int f0 = fl * 8;
    float v0 = fmaxf(a0 * sc[f0 + 0] + sh[f0 + 0], 0.f);
    float v1 = fmaxf(a1 * sc[f0 + 1] + sh[f0 + 1], 0.f);
    float v2 = fmaxf(a2 * sc[f0 + 2] + sh[f0 + 2], 0.f);
    float v3 = fmaxf(a3 * sc[f0 + 3] + sh[f0 + 3], 0.f);
    float v4 = fmaxf(a4 * sc[f0 + 4] + sh[f0 + 4], 0.f);
    float v5 = fmaxf(a5 * sc[f0 + 5] + sh[f0 + 5], 0.f);
    float v6 = fmaxf(a6 * sc[f0 + 6] + sh[f0 + 6], 0.f);
    float v7 = fmaxf(a7 * sc[f0 + 7] + sh[f0 + 7], 0.f);

    if (LAYER == 1) {
        if (lane < 8) {
            uint4 o;
            o.x = f2bf2(v0, v1); o.y = f2bf2(v2, v3);
            o.z = f2bf2(v4, v5); o.w = f2bf2(v6, v7);
            ((uint4*)out)[(size_t)wid * 8 + fl] = o;
        }
    } else {
        float tval = v0 * Wl[f0 + 0] + v1 * Wl[f0 + 1] + v2 * Wl[f0 + 2] + v3 * Wl[f0 + 3]
                   + v4 * Wl[f0 + 4] + v5 * Wl[f0 + 5] + v6 * Wl[f0 + 6] + v7 * Wl[f0 + 7];
        tval += __shfl_xor(tval, 1);
        tval += __shfl_xor(tval, 2);
        tval += __shfl_xor(tval, 4);
        if (lane == 0) {
            int is64 = *flag;
            int b = load_idx(bat, wid, is64);
            atomicAdd(&gsum[b], tval);
        }
    }
}

// ---------------- final: mean + linear bias ----------------
__global__ void k_final(const float* __restrict__ gsum, const int* __restrict__ gcnt,
                        const float* __restrict__ bl, float* __restrict__ outp, int G) {
    int g = blockIdx.x * blockDim.x + threadIdx.x;
    if (g < G) outp[g] = gsum[g] / fmaxf((float)gcnt[g], 1.0f) + bl[0];
}

extern "C" void kernel_launch(void* const* d_in, const int* in_sizes, int n_in,
                              void* d_out, int out_size, void* d_ws, size_t ws_size,
                              hipStream_t stream) {
    const float* x   = (const float*)d_in[0];
    const void*  ei  = d_in[1];
    const void*  bat = d_in[2];
    const float* W1  = (const float*)d_in[3];
    const float* b1  = (const float*)d_in[4];
    const float* g1  = (const float*)d_in[5];
    const float* be1 = (const float*)d_in[6];
    const float* m1  = (const float*)d_in[7];
    const float* v1  = (const float*)d_in[8];
    const float* W2  = (const float*)d_in[9];
    const float* b2  = (const float*)d_in[10];
    const float* g2  = (const float*)d_in[11];
    const float* be2 = (const float*)d_in[12];
    const float* m2  = (const float*)d_in[13];
    const float* v2  = (const float*)d_in[14];
    const float* Wl  = (const float*)d_in[15];
    const float* bl  = (const float*)d_in[16];
    float* outp = (float*)d_out;

    const int N = NN;
    const int E = in_sizes[1] / 2;
    const int G = out_size;

    // workspace carve-up (256B aligned)
    char* base = (char*)d_ws;
    size_t off = 0;
    auto alloc = [&](size_t bytes) { void* p = base + off; off = (off + bytes + 255) & ~(size_t)255; return p; };
    int*   flag    = (int*)  alloc(16);
    float* dinv    = (float*)alloc((size_t)N * 4);
    int*   counts  = (int*)  alloc((size_t)N * 4);
    int*   rp      = (int*)  alloc(((size_t)N + 1) * 4);
    int*   fillcnt = (int*)  alloc((size_t)N * 4);
    int*   partial = (int*)  alloc(1024);
    float* sc1     = (float*)alloc(HH * 4);
    float* sh1     = (float*)alloc(HH * 4);
    float* sc2     = (float*)alloc(HH * 4);
    float* sh2     = (float*)alloc(HH * 4);
    float* gsum    = (float*)alloc((size_t)G * 4);
    int*   gcnt    = (int*)  alloc((size_t)G * 4);
    int2*  cw      = (int2*) alloc((size_t)E * 8);
    unsigned short* hb1 = (unsigned short*)alloc((size_t)N * HH * 2);  // bf16 rows
    unsigned short* hb2 = (unsigned short*)alloc((size_t)N * HH * 2);  // bf16 rows
    (void)ws_size;

    // zero accumulators (fresh every call)
    hipMemsetAsync(counts, 0, (size_t)N * 4, stream);
    hipMemsetAsync(fillcnt, 0, (size_t)N * 4, stream);
    hipMemsetAsync(gsum, 0, (size_t)G * 4, stream);
    hipMemsetAsync(gcnt, 0, (size_t)G * 4, stream);

    k_detect<<<1, 64, 0, stream>>>((const unsigned*)ei, flag);

    int eb = (E + 255) / 256;
    k_count<<<eb, 256, 0, stream>>>(ei, E, flag, counts);

    int nb = (N + 255) / 256;
    k_dinv<<<nb, 256, 0, stream>>>(counts, dinv, bat, flag, gcnt, N);

    int nch = (N + 511) / 512;
    k_scan1<<<nch, 512, 0, stream>>>(counts, partial, N);
    k_scan2<<<1, 256, 0, stream>>>(partial, nch);
    k_scan3<<<nch, 512, 0, stream>>>(counts, partial, rp, N, E);

    k_fill<<<eb, 256, 0, stream>>>(ei, E, flag, dinv, rp, fillcnt, cw);

    k_prep<<<1, 64, 0, stream>>>(b1, g1, be1, m1, v1, b2, g2, be2, m2, v2,
                                 sc1, sh1, sc2, sh2);

    // layer 1: GEMM (f32 in -> bf16 rows), agg (bf16 gather, unrolled batch)
    k_gemm<FF, 8, float><<<(N + 7) / 8, 512, 0, stream>>>(x, W1, hb1, N);
    k_agg<1><<<(N + 3) / 4, 256, 0, stream>>>(hb1, cw, rp, dinv, sc1, sh1, hb2,
                                              bat, flag, Wl, gsum, N);
    // layer 2: GEMM (bf16 in -> bf16 rows), agg fused with pool
    k_gemm<HH, 8, unsigned short><<<(N + 7) / 8, 512, 0, stream>>>(hb2, W2, hb1, N);
    k_agg<2><<<(N + 3) / 4, 256, 0, stream>>>(hb1, cw, rp, dinv, sc2, sh2, nullptr,
                                              bat, flag, Wl, gsum, N);

    k_final<<<1, 256, 0, stream>>>(gsum, gcnt, bl, outp, G);
}

// Round 13
// 1242.731 us; speedup vs baseline: 1.0661x; 1.0661x over previous
//
#include <hip/hip_runtime.h>
#include <hip/hip_bf16.h>

// Problem constants (from reference)
#define NN 100000      // nodes
#define FF 128         // F_IN
#define HH 64          // HID
#define BN_EPS 1e-5f

// ---------------- dtype detection (int64 vs int32 edge/batch) ----------------
__global__ void k_detect(const unsigned* __restrict__ ei, int* __restrict__ flag) {
    if (threadIdx.x == 0 && blockIdx.x == 0) {
        unsigned o = 0;
        for (int i = 1; i < 32; i += 2) o |= ei[i];   // high words if int64
        *flag = (o == 0) ? 1 : 0;                      // 1 => int64
    }
}

__device__ __forceinline__ int load_idx(const void* p, int i, int is64) {
    return is64 ? (int)((const long long*)p)[i] : ((const int*)p)[i];
}

// ---------------- degree count ----------------
__global__ void k_count(const void* __restrict__ ei, int E, const int* __restrict__ flag,
                        int* __restrict__ counts) {
    int e = blockIdx.x * blockDim.x + threadIdx.x;
    if (e >= E) return;
    int is64 = *flag;
    int d = load_idx(ei, E + e, is64);   // dst row is second half
    atomicAdd(&counts[d], 1);
}

// ---------------- dinv + per-graph node counts ----------------
__global__ void k_dinv(const int* __restrict__ counts, float* __restrict__ dinv,
                       const void* __restrict__ bat, const int* __restrict__ flag,
                       int* __restrict__ gcnt, int N) {
    int i = blockIdx.x * blockDim.x + threadIdx.x;
    if (i >= N) return;
    float deg = (float)counts[i] + 1.0f;
    dinv[i] = rsqrtf(deg);
    int is64 = *flag;
    int b = load_idx(bat, i, is64);
    atomicAdd(&gcnt[b], 1);
}

// ---------------- 3-kernel exclusive scan (chunk = 512) ----------------
__global__ void k_scan1(const int* __restrict__ counts, int* __restrict__ partial, int N) {
    __shared__ int s[512];
    int t = threadIdx.x;
    int i = blockIdx.x * 512 + t;
    int v = (i < N) ? counts[i] : 0;
    s[t] = v; __syncthreads();
    for (int off = 256; off; off >>= 1) {
        if (t < off) s[t] += s[t + off];
        __syncthreads();
    }
    if (t == 0) partial[blockIdx.x] = s[0];
}

__global__ void k_scan2(int* __restrict__ partial, int nch) {
    __shared__ int s[256];
    int t = threadIdx.x;
    int v = (t < nch) ? partial[t] : 0;
    s[t] = v; __syncthreads();
    for (int off = 1; off < 256; off <<= 1) {
        int add = (t >= off) ? s[t - off] : 0;
        __syncthreads();
        s[t] += add;
        __syncthreads();
    }
    if (t < nch) partial[t] = s[t] - v;   // exclusive
}

__global__ void k_scan3(const int* __restrict__ counts, const int* __restrict__ partial,
                        int* __restrict__ rp, int N, int E) {
    __shared__ int s[512];
    int t = threadIdx.x;
    int i = blockIdx.x * 512 + t;
    int v = (i < N) ? counts[i] : 0;
    s[t] = v; __syncthreads();
    for (int off = 1; off < 512; off <<= 1) {
        int add = (t >= off) ? s[t - off] : 0;
        __syncthreads();
        s[t] += add;
        __syncthreads();
    }
    if (i < N) rp[i] = partial[blockIdx.x] + s[t] - v;
    if (i == N) rp[N] = E;
}

// ---------------- CSR fill: packed {src, w} ----------------
__global__ void k_fill(const void* __restrict__ ei, int E, const int* __restrict__ flag,
                       const float* __restrict__ dinv, const int* __restrict__ rp,
                       int* __restrict__ fillcnt, int2* __restrict__ cw) {
    int e = blockIdx.x * blockDim.x + threadIdx.x;
    if (e >= E) return;
    int is64 = *flag;
    int s = load_idx(ei, e, is64);
    int d = load_idx(ei, E + e, is64);
    float w = dinv[s] * dinv[d];
    int pos = rp[d] + atomicAdd(&fillcnt[d], 1);
    int2 p; p.x = s; p.y = __float_as_int(w);
    cw[pos] = p;
}

// ---------------- BN constant folding ----------------
__global__ void k_prep(const float* b1, const float* g1, const float* be1,
                       const float* m1, const float* v1,
                       const float* b2, const float* g2, const float* be2,
                       const float* m2, const float* v2,
                       float* sc1, float* sh1, float* sc2, float* sh2) {
    int f = threadIdx.x;
    if (f < HH) {
        float s1 = g1[f] * rsqrtf(v1[f] + BN_EPS);
        sc1[f] = s1; sh1[f] = (b1[f] - m1[f]) * s1 + be1[f];
        float s2 = g2[f] * rsqrtf(v2[f] + BN_EPS);
        sc2[f] = s2; sh2[f] = (b2[f] - m2[f]) * s2 + be2[f];
    }
}

// ---------------- dense GEMM: out[n][f] = sum_k x[n][k] * W[f][k] ----------------
template <int K, int NPB>
__global__ void k_gemm(const float* __restrict__ x, const float* __restrict__ W,
                       float* __restrict__ out, int N) {
    __shared__ float wT[K * (HH + 1)];
    __shared__ float xs[NPB * K];
    const int TB = NPB * 64;
    int t = threadIdx.x;
    for (int idx = t; idx < K * HH; idx += TB) {
        int f = idx / K, k = idx % K;
        wT[k * (HH + 1) + f] = W[idx];
    }
    int nb = blockIdx.x * NPB;
    for (int idx = t; idx < NPB * K; idx += TB) {
        int gi = nb * K + idx;
        xs[idx] = (gi < N * K) ? x[gi] : 0.0f;
    }
    __syncthreads();
    int f = t & 63, nl = t >> 6;
    float acc = 0.0f;
#pragma unroll
    for (int k = 0; k < K; k++)
        acc += xs[nl * K + k] * wT[k * (HH + 1) + f];
    int n = nb + nl;
    if (n < N) out[n * HH + f] = acc;
}

// ---------------- aggregation: cw-in-registers + shfl, 4-wide float4 gathers --
// Wave per node (R11 structure). One coalesced 512B load of 64 cw entries per
// batch; weights masked BEFORE shfl (exec-safe). Inner iteration widened to 4
// INDEPENDENT float4 gather instructions (16 edges, 64 cache lines issued
// before the first waitcnt) -> 2x the per-wave memory-level parallelism of
// R11, which Little's-law analysis showed is the binding resource (~18
// outstanding lines/CU). __launch_bounds__(256,8) pins 8 waves/SIMD.
template <int LAYER>
__global__ __launch_bounds__(256, 8) void k_agg(
        const float* __restrict__ h, const int2* __restrict__ cw,
        const int* __restrict__ rp, const float* __restrict__ dinv,
        const float* __restrict__ sc, const float* __restrict__ sh,
        float* __restrict__ out,
        const void* __restrict__ bat, const int* __restrict__ flag,
        const float* __restrict__ Wl, float* __restrict__ gsum, int N) {
    int wid = (int)((blockIdx.x * blockDim.x + threadIdx.x) >> 6);
    if (wid >= N) return;
    int lane = threadIdx.x & 63;
    int q = lane >> 4;       // edge slot within 4-edge group
    int fl = lane & 15;      // float4 chunk of the 64-float row
    const float4* __restrict__ h4 = (const float4*)h;

    int s = rp[wid], e = rp[wid + 1];
    float ax = 0.f, ay = 0.f, az = 0.f, aw = 0.f;

    for (int base = s; base < e; base += 64) {
        int navail = e - base; if (navail > 64) navail = 64;
        // one coalesced 512B load: lane l holds cw[base + min(l, navail-1)]
        int li = base + (lane < navail ? lane : navail - 1);
        int2 pk = cw[li];
        int   slane = pk.x;
        float wlane = (lane < navail) ? __int_as_float(pk.y) : 0.f;  // mask BEFORE shfl
        for (int g = 0; g < navail; g += 16) {
            int i0 = g + q, i1 = g + 4 + q, i2 = g + 8 + q, i3 = g + 12 + q;  // <= 63
            int s0 = __shfl(slane, i0);
            int s1 = __shfl(slane, i1);
            int s2 = __shfl(slane, i2);
            int s3 = __shfl(slane, i3);
            float w0 = __shfl(wlane, i0);
            float w1 = __shfl(wlane, i1);
            float w2 = __shfl(wlane, i2);
            float w3 = __shfl(wlane, i3);
            float4 r0 = h4[s0 * 16 + fl];
            float4 r1 = h4[s1 * 16 + fl];
            float4 r2 = h4[s2 * 16 + fl];
            float4 r3 = h4[s3 * 16 + fl];
            ax += w0 * r0.x + w1 * r1.x + w2 * r2.x + w3 * r3.x;
            ay += w0 * r0.y + w1 * r1.y + w2 * r2.y + w3 * r3.y;
            az += w0 * r0.z + w1 * r1.z + w2 * r2.z + w3 * r3.z;
            aw += w0 * r0.w + w1 * r1.w + w2 * r2.w + w3 * r3.w;
        }
    }
    // combine the 4 edge slots (lane bits 4,5)
    ax += __shfl_xor(ax, 16); ay += __shfl_xor(ay, 16);
    az += __shfl_xor(az, 16); aw += __shfl_xor(aw, 16);
    ax += __shfl_xor(ax, 32); ay += __shfl_xor(ay, 32);
    az += __shfl_xor(az, 32); aw += __shfl_xor(aw, 32);

    // self-loop term (added once, post-reduce)
    float di = dinv[wid];
    float di2 = di * di;
    float4 sr = h4[wid * 16 + fl];
    ax += di2 * sr.x; ay += di2 * sr.y; az += di2 * sr.z; aw += di2 * sr.w;

    // BN + ReLU on this lane's 4 features
    int f0 = fl * 4;
    float vx = fmaxf(ax * sc[f0 + 0] + sh[f0 + 0], 0.f);
    float vy = fmaxf(ay * sc[f0 + 1] + sh[f0 + 1], 0.f);
    float vz = fmaxf(az * sc[f0 + 2] + sh[f0 + 2], 0.f);
    float vw = fmaxf(aw * sc[f0 + 3] + sh[f0 + 3], 0.f);

    if (LAYER == 1) {
        if (lane < 16) {
            float4 o; o.x = vx; o.y = vy; o.z = vz; o.w = vw;
            ((float4*)out)[wid * 16 + fl] = o;
        }
    } else {
        float tval = vx * Wl[f0] + vy * Wl[f0 + 1] + vz * Wl[f0 + 2] + vw * Wl[f0 + 3];
        tval += __shfl_xor(tval, 1);
        tval += __shfl_xor(tval, 2);
        tval += __shfl_xor(tval, 4);
        tval += __shfl_xor(tval, 8);
        if (lane == 0) {
            int is64 = *flag;
            int b = load_idx(bat, wid, is64);
            atomicAdd(&gsum[b], tval);
        }
    }
}

// ---------------- final: mean + linear bias ----------------
__global__ void k_final(const float* __restrict__ gsum, const int* __restrict__ gcnt,
                        const float* __restrict__ bl, float* __restrict__ outp, int G) {
    int g = blockIdx.x * blockDim.x + threadIdx.x;
    if (g < G) outp[g] = gsum[g] / fmaxf((float)gcnt[g], 1.0f) + bl[0];
}

extern "C" void kernel_launch(void* const* d_in, const int* in_sizes, int n_in,
                              void* d_out, int out_size, void* d_ws, size_t ws_size,
                              hipStream_t stream) {
    const float* x   = (const float*)d_in[0];
    const void*  ei  = d_in[1];
    const void*  bat = d_in[2];
    const float* W1  = (const float*)d_in[3];
    const float* b1  = (const float*)d_in[4];
    const float* g1  = (const float*)d_in[5];
    const float* be1 = (const float*)d_in[6];
    const float* m1  = (const float*)d_in[7];
    const float* v1  = (const float*)d_in[8];
    const float* W2  = (const float*)d_in[9];
    const float* b2  = (const float*)d_in[10];
    const float* g2  = (const float*)d_in[11];
    const float* be2 = (const float*)d_in[12];
    const float* m2  = (const float*)d_in[13];
    const float* v2  = (const float*)d_in[14];
    const float* Wl  = (const float*)d_in[15];
    const float* bl  = (const float*)d_in[16];
    float* outp = (float*)d_out;

    const int N = NN;
    const int E = in_sizes[1] / 2;
    const int G = out_size;

    // workspace carve-up (256B aligned)
    char* base = (char*)d_ws;
    size_t off = 0;
    auto alloc = [&](size_t bytes) { void* p = base + off; off = (off + bytes + 255) & ~(size_t)255; return p; };
    int*   flag    = (int*)  alloc(16);
    float* dinv    = (float*)alloc((size_t)N * 4);
    int*   counts  = (int*)  alloc((size_t)N * 4);
    int*   rp      = (int*)  alloc(((size_t)N + 1) * 4);
    int*   fillcnt = (int*)  alloc((size_t)N * 4);
    int*   partial = (int*)  alloc(1024);
    float* sc1     = (float*)alloc(HH * 4);
    float* sh1     = (float*)alloc(HH * 4);
    float* sc2     = (float*)alloc(HH * 4);
    float* sh2     = (float*)alloc(HH * 4);
    float* gsum    = (float*)alloc((size_t)G * 4);
    int*   gcnt    = (int*)  alloc((size_t)G * 4);
    int2*  cw      = (int2*) alloc((size_t)E * 8);
    float* bufA    = (float*)alloc((size_t)N * HH * 4);   // h1, later h2
    float* bufB    = (float*)alloc((size_t)N * HH * 4);   // h2in
    (void)ws_size;

    // zero accumulators (fresh every call)
    hipMemsetAsync(counts, 0, (size_t)N * 4, stream);
    hipMemsetAsync(fillcnt, 0, (size_t)N * 4, stream);
    hipMemsetAsync(gsum, 0, (size_t)G * 4, stream);
    hipMemsetAsync(gcnt, 0, (size_t)G * 4, stream);

    k_detect<<<1, 64, 0, stream>>>((const unsigned*)ei, flag);

    int eb = (E + 255) / 256;
    k_count<<<eb, 256, 0, stream>>>(ei, E, flag, counts);

    int nb = (N + 255) / 256;
    k_dinv<<<nb, 256, 0, stream>>>(counts, dinv, bat, flag, gcnt, N);

    int nch = (N + 511) / 512;
    k_scan1<<<nch, 512, 0, stream>>>(counts, partial, N);
    k_scan2<<<1, 256, 0, stream>>>(partial, nch);
    k_scan3<<<nch, 512, 0, stream>>>(counts, partial, rp, N, E);

    k_fill<<<eb, 256, 0, stream>>>(ei, E, flag, dinv, rp, fillcnt, cw);

    k_prep<<<1, 64, 0, stream>>>(b1, g1, be1, m1, v1, b2, g2, be2, m2, v2,
                                 sc1, sh1, sc2, sh2);

    // layer 1
    k_gemm<FF, 8><<<(N + 7) / 8, 512, 0, stream>>>(x, W1, bufA, N);
    k_agg<1><<<(N + 3) / 4, 256, 0, stream>>>(bufA, cw, rp, dinv, sc1, sh1, bufB,
                                              bat, flag, Wl, gsum, N);
    // layer 2
    k_gemm<HH, 8><<<(N + 7) / 8, 512, 0, stream>>>(bufB, W2, bufA, N);
    k_agg<2><<<(N + 3) / 4, 256, 0, stream>>>(bufA, cw, rp, dinv, sc2, sh2, nullptr,
                                              bat, flag, Wl, gsum, N);

    k_final<<<1, 256, 0, stream>>>(gsum, gcnt, bl, outp, G);
}

// Round 14
// 1208.691 us; speedup vs baseline: 1.0961x; 1.0282x over previous
//
#include <hip/hip_runtime.h>
#include <hip/hip_bf16.h>

// Problem constants (from reference)
#define NN 100000      // nodes
#define FF 128         // F_IN
#define HH 64          // HID
#define BN_EPS 1e-5f

typedef float vfloat4 __attribute__((ext_vector_type(4)));

// ---------------- dtype detection (int64 vs int32 edge/batch) ----------------
__global__ void k_detect(const unsigned* __restrict__ ei, int* __restrict__ flag) {
    if (threadIdx.x == 0 && blockIdx.x == 0) {
        unsigned o = 0;
        for (int i = 1; i < 32; i += 2) o |= ei[i];   // high words if int64
        *flag = (o == 0) ? 1 : 0;                      // 1 => int64
    }
}

__device__ __forceinline__ int load_idx(const void* p, int i, int is64) {
    return is64 ? (int)((const long long*)p)[i] : ((const int*)p)[i];
}

// ---------------- degree count ----------------
__global__ void k_count(const void* __restrict__ ei, int E, const int* __restrict__ flag,
                        int* __restrict__ counts) {
    int e = blockIdx.x * blockDim.x + threadIdx.x;
    if (e >= E) return;
    int is64 = *flag;
    int d = load_idx(ei, E + e, is64);   // dst row is second half
    atomicAdd(&counts[d], 1);
}

// ---------------- dinv + per-graph node counts ----------------
__global__ void k_dinv(const int* __restrict__ counts, float* __restrict__ dinv,
                       const void* __restrict__ bat, const int* __restrict__ flag,
                       int* __restrict__ gcnt, int N) {
    int i = blockIdx.x * blockDim.x + threadIdx.x;
    if (i >= N) return;
    float deg = (float)counts[i] + 1.0f;
    dinv[i] = rsqrtf(deg);
    int is64 = *flag;
    int b = load_idx(bat, i, is64);
    atomicAdd(&gcnt[b], 1);
}

// ---------------- 3-kernel exclusive scan (chunk = 512) ----------------
__global__ void k_scan1(const int* __restrict__ counts, int* __restrict__ partial, int N) {
    __shared__ int s[512];
    int t = threadIdx.x;
    int i = blockIdx.x * 512 + t;
    int v = (i < N) ? counts[i] : 0;
    s[t] = v; __syncthreads();
    for (int off = 256; off; off >>= 1) {
        if (t < off) s[t] += s[t + off];
        __syncthreads();
    }
    if (t == 0) partial[blockIdx.x] = s[0];
}

__global__ void k_scan2(int* __restrict__ partial, int nch) {
    __shared__ int s[256];
    int t = threadIdx.x;
    int v = (t < nch) ? partial[t] : 0;
    s[t] = v; __syncthreads();
    for (int off = 1; off < 256; off <<= 1) {
        int add = (t >= off) ? s[t - off] : 0;
        __syncthreads();
        s[t] += add;
        __syncthreads();
    }
    if (t < nch) partial[t] = s[t] - v;   // exclusive
}

__global__ void k_scan3(const int* __restrict__ counts, const int* __restrict__ partial,
                        int* __restrict__ rp, int N, int E) {
    __shared__ int s[512];
    int t = threadIdx.x;
    int i = blockIdx.x * 512 + t;
    int v = (i < N) ? counts[i] : 0;
    s[t] = v; __syncthreads();
    for (int off = 1; off < 512; off <<= 1) {
        int add = (t >= off) ? s[t - off] : 0;
        __syncthreads();
        s[t] += add;
        __syncthreads();
    }
    if (i < N) rp[i] = partial[blockIdx.x] + s[t] - v;
    if (i == N) rp[N] = E;
}

// ---------------- CSR fill: packed {src, w} ----------------
__global__ void k_fill(const void* __restrict__ ei, int E, const int* __restrict__ flag,
                       const float* __restrict__ dinv, const int* __restrict__ rp,
                       int* __restrict__ fillcnt, int2* __restrict__ cw) {
    int e = blockIdx.x * blockDim.x + threadIdx.x;
    if (e >= E) return;
    int is64 = *flag;
    int s = load_idx(ei, e, is64);
    int d = load_idx(ei, E + e, is64);
    float w = dinv[s] * dinv[d];
    int pos = rp[d] + atomicAdd(&fillcnt[d], 1);
    int2 p; p.x = s; p.y = __float_as_int(w);
    cw[pos] = p;
}

// ---------------- BN constant folding ----------------
__global__ void k_prep(const float* b1, const float* g1, const float* be1,
                       const float* m1, const float* v1,
                       const float* b2, const float* g2, const float* be2,
                       const float* m2, const float* v2,
                       float* sc1, float* sh1, float* sc2, float* sh2) {
    int f = threadIdx.x;
    if (f < HH) {
        float s1 = g1[f] * rsqrtf(v1[f] + BN_EPS);
        sc1[f] = s1; sh1[f] = (b1[f] - m1[f]) * s1 + be1[f];
        float s2 = g2[f] * rsqrtf(v2[f] + BN_EPS);
        sc2[f] = s2; sh2[f] = (b2[f] - m2[f]) * s2 + be2[f];
    }
}

// ---------------- dense GEMM: out[n][f] = sum_k x[n][k] * W[f][k] ----------------
template <int K, int NPB>
__global__ void k_gemm(const float* __restrict__ x, const float* __restrict__ W,
                       float* __restrict__ out, int N) {
    __shared__ float wT[K * (HH + 1)];
    __shared__ float xs[NPB * K];
    const int TB = NPB * 64;
    int t = threadIdx.x;
    for (int idx = t; idx < K * HH; idx += TB) {
        int f = idx / K, k = idx % K;
        wT[k * (HH + 1) + f] = W[idx];
    }
    int nb = blockIdx.x * NPB;
    for (int idx = t; idx < NPB * K; idx += TB) {
        int gi = nb * K + idx;
        xs[idx] = (gi < N * K) ? x[gi] : 0.0f;
    }
    __syncthreads();
    int f = t & 63, nl = t >> 6;
    float acc = 0.0f;
#pragma unroll
    for (int k = 0; k < K; k++)
        acc += xs[nl * K + k] * wT[k * (HH + 1) + f];
    int n = nb + nl;
    if (n < N) out[n * HH + f] = acc;
}

// ---------------- aggregation: R11 structure + NON-TEMPORAL row gathers -------
// Wave per node. One coalesced 512B load of 64 cw entries per batch; weights
// masked BEFORE shfl (exec-safe). The h row gathers use
// __builtin_nontemporal_load (global_load_dwordx4 ... nt): the 25.6MB random
// gather stream has ~0% L1 hit rate, and the ~23-outstanding-lines/CU cap
// measured via Little's law matches an L1 MSHR limit — nt loads skip L1
// allocation, targeting the deeper L2/TA queues.
template <int LAYER>
__global__ void k_agg(const float* __restrict__ h, const int2* __restrict__ cw,
                      const int* __restrict__ rp, const float* __restrict__ dinv,
                      const float* __restrict__ sc, const float* __restrict__ sh,
                      float* __restrict__ out,
                      const void* __restrict__ bat, const int* __restrict__ flag,
                      const float* __restrict__ Wl, float* __restrict__ gsum, int N) {
    int wid = (int)((blockIdx.x * blockDim.x + threadIdx.x) >> 6);
    if (wid >= N) return;
    int lane = threadIdx.x & 63;
    int q = lane >> 4;       // edge slot within 4-edge group
    int fl = lane & 15;      // float4 chunk of the 64-float row
    const vfloat4* __restrict__ hv = (const vfloat4*)h;

    int s = rp[wid], e = rp[wid + 1];
    float ax = 0.f, ay = 0.f, az = 0.f, aw = 0.f;

    for (int base = s; base < e; base += 64) {
        int navail = e - base; if (navail > 64) navail = 64;
        // one coalesced 512B load: lane l holds cw[base + min(l, navail-1)]
        int li = base + (lane < navail ? lane : navail - 1);
        int2 pk = cw[li];
        int   slane = pk.x;
        float wlane = (lane < navail) ? __int_as_float(pk.y) : 0.f;  // mask BEFORE shfl
        for (int g = 0; g < navail; g += 8) {
            int i0 = g + q, i1 = g + 4 + q;          // always <= 63
            int s0 = __shfl(slane, i0);
            int s1 = __shfl(slane, i1);
            float w0 = __shfl(wlane, i0);
            float w1 = __shfl(wlane, i1);
            vfloat4 r0 = __builtin_nontemporal_load(hv + s0 * 16 + fl);
            vfloat4 r1 = __builtin_nontemporal_load(hv + s1 * 16 + fl);
            ax += w0 * r0.x + w1 * r1.x;
            ay += w0 * r0.y + w1 * r1.y;
            az += w0 * r0.z + w1 * r1.z;
            aw += w0 * r0.w + w1 * r1.w;
        }
    }
    // combine the 4 edge slots (lane bits 4,5)
    ax += __shfl_xor(ax, 16); ay += __shfl_xor(ay, 16);
    az += __shfl_xor(az, 16); aw += __shfl_xor(aw, 16);
    ax += __shfl_xor(ax, 32); ay += __shfl_xor(ay, 32);
    az += __shfl_xor(az, 32); aw += __shfl_xor(aw, 32);

    // self-loop term (added once, post-reduce)
    float di = dinv[wid];
    float di2 = di * di;
    vfloat4 sr = hv[wid * 16 + fl];
    ax += di2 * sr.x; ay += di2 * sr.y; az += di2 * sr.z; aw += di2 * sr.w;

    // BN + ReLU on this lane's 4 features
    int f0 = fl * 4;
    float vx = fmaxf(ax * sc[f0 + 0] + sh[f0 + 0], 0.f);
    float vy = fmaxf(ay * sc[f0 + 1] + sh[f0 + 1], 0.f);
    float vz = fmaxf(az * sc[f0 + 2] + sh[f0 + 2], 0.f);
    float vw = fmaxf(aw * sc[f0 + 3] + sh[f0 + 3], 0.f);

    if (LAYER == 1) {
        if (lane < 16) {
            float4 o; o.x = vx; o.y = vy; o.z = vz; o.w = vw;
            ((float4*)out)[wid * 16 + fl] = o;
        }
    } else {
        float tval = vx * Wl[f0] + vy * Wl[f0 + 1] + vz * Wl[f0 + 2] + vw * Wl[f0 + 3];
        tval += __shfl_xor(tval, 1);
        tval += __shfl_xor(tval, 2);
        tval += __shfl_xor(tval, 4);
        tval += __shfl_xor(tval, 8);
        if (lane == 0) {
            int is64 = *flag;
            int b = load_idx(bat, wid, is64);
            atomicAdd(&gsum[b], tval);
        }
    }
}

// ---------------- final: mean + linear bias ----------------
__global__ void k_final(const float* __restrict__ gsum, const int* __restrict__ gcnt,
                        const float* __restrict__ bl, float* __restrict__ outp, int G) {
    int g = blockIdx.x * blockDim.x + threadIdx.x;
    if (g < G) outp[g] = gsum[g] / fmaxf((float)gcnt[g], 1.0f) + bl[0];
}

extern "C" void kernel_launch(void* const* d_in, const int* in_sizes, int n_in,
                              void* d_out, int out_size, void* d_ws, size_t ws_size,
                              hipStream_t stream) {
    const float* x   = (const float*)d_in[0];
    const void*  ei  = d_in[1];
    const void*  bat = d_in[2];
    const float* W1  = (const float*)d_in[3];
    const float* b1  = (const float*)d_in[4];
    const float* g1  = (const float*)d_in[5];
    const float* be1 = (const float*)d_in[6];
    const float* m1  = (const float*)d_in[7];
    const float* v1  = (const float*)d_in[8];
    const float* W2  = (const float*)d_in[9];
    const float* b2  = (const float*)d_in[10];
    const float* g2  = (const float*)d_in[11];
    const float* be2 = (const float*)d_in[12];
    const float* m2  = (const float*)d_in[13];
    const float* v2  = (const float*)d_in[14];
    const float* Wl  = (const float*)d_in[15];
    const float* bl  = (const float*)d_in[16];
    float* outp = (float*)d_out;

    const int N = NN;
    const int E = in_sizes[1] / 2;
    const int G = out_size;

    // workspace carve-up (256B aligned)
    char* base = (char*)d_ws;
    size_t off = 0;
    auto alloc = [&](size_t bytes) { void* p = base + off; off = (off + bytes + 255) & ~(size_t)255; return p; };
    int*   flag    = (int*)  alloc(16);
    float* dinv    = (float*)alloc((size_t)N * 4);
    int*   counts  = (int*)  alloc((size_t)N * 4);
    int*   rp      = (int*)  alloc(((size_t)N + 1) * 4);
    int*   fillcnt = (int*)  alloc((size_t)N * 4);
    int*   partial = (int*)  alloc(1024);
    float* sc1     = (float*)alloc(HH * 4);
    float* sh1     = (float*)alloc(HH * 4);
    float* sc2     = (float*)alloc(HH * 4);
    float* sh2     = (float*)alloc(HH * 4);
    float* gsum    = (float*)alloc((size_t)G * 4);
    int*   gcnt    = (int*)  alloc((size_t)G * 4);
    int2*  cw      = (int2*) alloc((size_t)E * 8);
    float* bufA    = (float*)alloc((size_t)N * HH * 4);   // h1, later h2
    float* bufB    = (float*)alloc((size_t)N * HH * 4);   // h2in
    (void)ws_size;

    // zero accumulators (fresh every call)
    hipMemsetAsync(counts, 0, (size_t)N * 4, stream);
    hipMemsetAsync(fillcnt, 0, (size_t)N * 4, stream);
    hipMemsetAsync(gsum, 0, (size_t)G * 4, stream);
    hipMemsetAsync(gcnt, 0, (size_t)G * 4, stream);

    k_detect<<<1, 64, 0, stream>>>((const unsigned*)ei, flag);

    int eb = (E + 255) / 256;
    k_count<<<eb, 256, 0, stream>>>(ei, E, flag, counts);

    int nb = (N + 255) / 256;
    k_dinv<<<nb, 256, 0, stream>>>(counts, dinv, bat, flag, gcnt, N);

    int nch = (N + 511) / 512;
    k_scan1<<<nch, 512, 0, stream>>>(counts, partial, N);
    k_scan2<<<1, 256, 0, stream>>>(partial, nch);
    k_scan3<<<nch, 512, 0, stream>>>(counts, partial, rp, N, E);

    k_fill<<<eb, 256, 0, stream>>>(ei, E, flag, dinv, rp, fillcnt, cw);

    k_prep<<<1, 64, 0, stream>>>(b1, g1, be1, m1, v1, b2, g2, be2, m2, v2,
                                 sc1, sh1, sc2, sh2);

    // layer 1
    k_gemm<FF, 8><<<(N + 7) / 8, 512, 0, stream>>>(x, W1, bufA, N);
    k_agg<1><<<(N + 3) / 4, 256, 0, stream>>>(bufA, cw, rp, dinv, sc1, sh1, bufB,
                                              bat, flag, Wl, gsum, N);
    // layer 2
    k_gemm<HH, 8><<<(N + 7) / 8, 512, 0, stream>>>(bufB, W2, bufA, N);
    k_agg<2><<<(N + 3) / 4, 256, 0, stream>>>(bufA, cw, rp, dinv, sc2, sh2, nullptr,
                                              bat, flag, Wl, gsum, N);

    k_final<<<1, 256, 0, stream>>>(gsum, gcnt, bl, outp, G);
}